// Round 12
// baseline (189.481 us; speedup 1.0000x reference)
//
#include <hip/hip_runtime.h>
#include <hip/hip_bf16.h>

typedef __bf16 bf16;
typedef __attribute__((ext_vector_type(8))) __bf16 bf16x8;
typedef __attribute__((ext_vector_type(4))) __bf16 bf16x4;
typedef __attribute__((ext_vector_type(16))) float f32x16;

#define N_ROWS 16384
#define DIM 256
#define NT 128            /* 128-row tiles */
#define NJC 256           /* 64-col tiles */
#define LSTRIP 16
#define NSTRIPS 1088      /* sum_{it=0..127} ceil((256-2it)/16) = 8*(1+..+16) */
#define SQK1 4.53981608f  /* sqrt(1/(0.07*ln2)): A pre-scaled so e^{z} = 2^{dot'} */
#define LN2F 0.69314718056f

#define WS_T_OFF (N_ROWS * DIM * 2)
#define WS_D_OFF (WS_T_OFF + N_ROWS * 4)
#define WS_DONE_OFF (WS_D_OFF + N_ROWS * 4)

#define GLOAD_LDS(g, l)                                        \
    __builtin_amdgcn_global_load_lds(                          \
        (const __attribute__((address_space(1))) void*)(g),    \
        (__attribute__((address_space(3))) void*)(l), 16, 0, 0)

// Kernel 1: L2-normalize rows, scale by SQK1, emit bf16 A' to ws. Zeros T[],
// done-counter, d_out. Dg[row] = s2' = sum(bf16(SQK1*a)^2) = the MFMA
// diagonal, so its bf16 rounding cancels: loss_i = ln2*(log2(T'_i) - s2'_i).
__global__ void __launch_bounds__(256) normalize_kernel(const float* __restrict__ in,
                                                        bf16* __restrict__ out,
                                                        float* __restrict__ Tg,
                                                        float* __restrict__ Dg,
                                                        int* __restrict__ done,
                                                        float* __restrict__ loss_out) {
    if (blockIdx.x == 0 && threadIdx.x == 0) { loss_out[0] = 0.0f; done[0] = 0; }
    if (blockIdx.x < 64) Tg[blockIdx.x * 256 + threadIdx.x] = 0.0f;

    const int row  = blockIdx.x * 4 + (threadIdx.x >> 6);
    const int lane = threadIdx.x & 63;
    const float4* rp = (const float4*)(in + (size_t)row * DIM);
    float4 v = rp[lane];
    float ss = v.x * v.x + v.y * v.y + v.z * v.z + v.w * v.w;
#pragma unroll
    for (int m = 1; m < 64; m <<= 1) ss += __shfl_xor(ss, m, 64);
    float inv = SQK1 / fmaxf(sqrtf(ss), 1e-12f);
    bf16x4 o;
    o[0] = (bf16)(v.x * inv);
    o[1] = (bf16)(v.y * inv);
    o[2] = (bf16)(v.z * inv);
    o[3] = (bf16)(v.w * inv);
    *(bf16x4*)(out + (size_t)row * DIM + lane * 4) = o;

    float f0 = (float)o[0], f1 = (float)o[1], f2 = (float)o[2], f3 = (float)o[3];
    float s2 = f0 * f0 + f1 * f1 + f2 * f2 + f3 * f3;
#pragma unroll
    for (int m = 1; m < 64; m <<= 1) s2 += __shfl_xor(s2, m, 64);
    if (lane == 0) Dg[row] = s2;
}

// Tree-reduce 16 floats across the 32 `lo` lanes; every lane ends with the
// full sum for register index r = (lo>>1)&15. (Correctness-proven R4-R11.)
#define TREE16(R, out)                                                     \
    do {                                                                   \
        float w8[8], w4[4], w2[2], w1, g_;                                 \
        _Pragma("unroll") for (int i_ = 0; i_ < 8; ++i_) {                 \
            g_ = (lo & 16) ? R[i_] : R[i_ + 8];                            \
            w8[i_] = ((lo & 16) ? R[i_ + 8] : R[i_]) + __shfl_xor(g_, 16); \
        }                                                                  \
        _Pragma("unroll") for (int i_ = 0; i_ < 4; ++i_) {                 \
            g_ = (lo & 8) ? w8[i_] : w8[i_ + 4];                           \
            w4[i_] = ((lo & 8) ? w8[i_ + 4] : w8[i_]) + __shfl_xor(g_, 8); \
        }                                                                  \
        _Pragma("unroll") for (int i_ = 0; i_ < 2; ++i_) {                 \
            g_ = (lo & 4) ? w4[i_] : w4[i_ + 2];                           \
            w2[i_] = ((lo & 4) ? w4[i_ + 2] : w4[i_]) + __shfl_xor(g_, 4); \
        }                                                                  \
        g_ = (lo & 2) ? w2[0] : w2[1];                                     \
        w1 = ((lo & 2) ? w2[1] : w2[0]) + __shfl_xor(g_, 2);               \
        out = w1 + __shfl_xor(w1, 1);                                      \
    } while (0)

// Kernel 2: symmetric A'A'^T + softmax denominator + (last block) final loss.
// R11 core unchanged: 512 thr = 4 rg(32 rows) x 2 cg(32 cols) per 128x64
// tile; af persistent in AGPRs (plain loads — remat across the asm memory-
// clobber barriers is illegal, volatile unnecessary); B staged to LDS dbuf
// via global_load_lds w=16 + XOR source swizzle; raw s_barrier + vmcnt(4).
// New: LSTRIP=16 (af traffic halved, 1088 blocks), CsAcc via LDS atomics,
// last-block-done final reduction (removes a kernel launch).
__global__ void __launch_bounds__(512, 4)
loss_kernel(const bf16* __restrict__ A, float* __restrict__ Tg,
            const float* __restrict__ Dg, int* __restrict__ done,
            float* __restrict__ loss_out) {
    __shared__ bf16 Bs0[64 * DIM];       // 32 KB
    __shared__ bf16 Bs1[64 * DIM];       // 32 KB
    __shared__ float CsAcc[LSTRIP][64];  // 4 KB
    __shared__ float red2[8];
    __shared__ int lastflag;

    const int tid = threadIdx.x;
    const int w  = tid >> 6;
    const int l  = tid & 63;
    const int lo = l & 31, hi = l >> 5;
    const int rg = w >> 1;   // row-group: rows rg*32..+31
    const int cg = w & 1;    // col-group: cols cg*32..+31

    // strip decode: (it, chunk of up to 16 col-tiles starting at jc0 >= 2*it)
    int it = 0, rem = blockIdx.x;
    for (;;) {
        int nch = (NJC - 2 * it + LSTRIP - 1) >> 4;
        if (rem < nch) break;
        rem -= nch;
        ++it;
    }
    const int jc0 = 2 * it + rem * LSTRIP;
    const int jc1 = (jc0 + LSTRIP < NJC) ? (jc0 + LSTRIP) : NJC;

    // persistent A fragments (A-op: m=lo, k=hi*8+j); plain loads, static idx
    bf16x8 af[16];
    {
        const bf16* ap = A + (size_t)(it * 128 + rg * 32 + lo) * DIM + hi * 8;
#pragma unroll
        for (int k = 0; k < 16; ++k)
            af[k] = *(const bf16x8*)(ap + k * 16);
    }

    float s0[16];
#pragma unroll
    for (int r = 0; r < 16; ++r) s0[r] = 0.f;

    // zero the per-strip col accumulator
    for (int i = tid; i < LSTRIP * 64; i += 512) ((float*)CsAcc)[i] = 0.f;
    __syncthreads();

    // DMA lane constants (wave w stages B rows w*8..+7 in 4 instrs, 2 rows
    // each; slot s of row r holds global chunk c = (s&24)|((s&7)^(r&7)))
    const int s_dma = l & 31;
    const int rl    = l >> 5;
    int vo[4];
#pragma unroll
    for (int q = 0; q < 4; ++q) {
        const int c = (s_dma & 24) | ((s_dma & 7) ^ ((q * 2 + rl) & 7));
        vo[q] = rl * DIM + c * 8;
    }

    const int rbase = (cg * 32 + lo) * DIM;
    const int mx7 = lo & 7;

#define ISSUE(jcn, BUF)                                                      \
    do {                                                                     \
        const bf16* tb_ = A + (size_t)((jcn) * 64 + w * 8) * DIM;            \
        bf16* lb_ = &BUF[(w * 8) * DIM];                                     \
        _Pragma("unroll") for (int q_ = 0; q_ < 4; ++q_) {                   \
            GLOAD_LDS(tb_ + (q_ * 2) * DIM + vo[q_],                         \
                      lb_ + (q_ * 2) * DIM);                                 \
        }                                                                    \
    } while (0)

#define TILE_BODY(BR, BW, jc, t)                                             \
    do {                                                                     \
        asm volatile("s_barrier" ::: "memory");                              \
        if ((jc) + 1 < jc1) {                                                \
            ISSUE((jc) + 1, BW);                                             \
            asm volatile("s_waitcnt vmcnt(4)" ::: "memory");                 \
        } else {                                                             \
            asm volatile("s_waitcnt vmcnt(0)" ::: "memory");                 \
        }                                                                    \
        asm volatile("s_barrier" ::: "memory");                              \
        f32x16 c0;                                                           \
        _Pragma("unroll") for (int r_ = 0; r_ < 16; ++r_) c0[r_] = 0.f;      \
        _Pragma("unroll") for (int k_ = 0; k_ < 16; ++k_) {                  \
            const int cc_ = k_ * 2 + hi;                                     \
            const int slot_ = (cc_ & 24) | ((cc_ & 7) ^ mx7);                \
            bf16x8 b_ = *(const bf16x8*)&BR[rbase + slot_ * 8];              \
            c0 = __builtin_amdgcn_mfma_f32_32x32x16_bf16(af[k_], b_, c0, 0, 0, 0); \
        }                                                                    \
        float cs_ = 0.f;                                                     \
        _Pragma("unroll") for (int r_ = 0; r_ < 16; ++r_) {                  \
            float e_ = __builtin_amdgcn_exp2f(c0[r_]);                       \
            s0[r_] += e_;                                                    \
            cs_ += e_;                                                       \
        }                                                                    \
        cs_ += __shfl_xor(cs_, 32);                                          \
        if (hi == 0) atomicAdd(&CsAcc[t][cg * 32 + lo], cs_);                \
    } while (0)

    ISSUE(jc0, Bs0);
    int jc = jc0;
    while (jc < jc1) {
        TILE_BODY(Bs0, Bs1, jc, jc - jc0);
        ++jc;
        if (jc >= jc1) break;
        TILE_BODY(Bs1, Bs0, jc, jc - jc0);
        ++jc;
    }

    // strip end: row sums. C/D row = (r&3)+8*(r>>2)+4*hi.
    float t0;
    TREE16(s0, t0);
    const int r = (lo >> 1) & 15;
    const int rowoff = (r & 3) + 8 * (r >> 2) + 4 * hi;
    if ((l & 1) == 0)
        atomicAdd(&Tg[it * 128 + rg * 32 + rowoff], t0);

    // col-sum flush (skip diagonal 128x128 super-tile: jc>>1 == it)
    __syncthreads();
    const int nt_strip = jc1 - jc0;
    for (int i = tid; i < nt_strip * 64; i += 512) {
        const int t = i >> 6, col = i & 63;
        if (((jc0 + t) >> 1) != it)
            atomicAdd(&Tg[(jc0 + t) * 64 + col], CsAcc[t][col]);
    }

    // ---- last-block final reduction (replaces final_kernel launch) ----
    __syncthreads();  // drain all this block's vmem (incl. atomics) pre-flag
    if (tid == 0) {
        int old = __hip_atomic_fetch_add(done, 1, __ATOMIC_ACQ_REL,
                                         __HIP_MEMORY_SCOPE_AGENT);
        lastflag = (old == NSTRIPS - 1);
    }
    __syncthreads();
    if (lastflag) {
        float acc = 0.f;
        for (int i = tid; i < N_ROWS; i += 512) {
            float t = __hip_atomic_load(&Tg[i], __ATOMIC_RELAXED,
                                        __HIP_MEMORY_SCOPE_AGENT);
            acc += __log2f(t) - Dg[i];
        }
#pragma unroll
        for (int m = 1; m < 64; m <<= 1) acc += __shfl_xor(acc, m, 64);
        if (l == 0) red2[w] = acc;
        __syncthreads();
        if (tid == 0) {
            float s = red2[0] + red2[1] + red2[2] + red2[3] +
                      red2[4] + red2[5] + red2[6] + red2[7];
            loss_out[0] = LN2F * s * (1.0f / (float)N_ROWS);
        }
    }
#undef ISSUE
#undef TILE_BODY
}

extern "C" void kernel_launch(void* const* d_in, const int* in_sizes, int n_in,
                              void* d_out, int out_size, void* d_ws, size_t ws_size,
                              hipStream_t stream) {
    const float* emb = (const float*)d_in[0];
    float* out = (float*)d_out;
    bf16* Abf = (bf16*)d_ws;
    float* Tg = (float*)((char*)d_ws + WS_T_OFF);
    float* Dg = (float*)((char*)d_ws + WS_D_OFF);
    int* done = (int*)((char*)d_ws + WS_DONE_OFF);

    hipLaunchKernelGGL(normalize_kernel, dim3(N_ROWS / 4), dim3(256), 0, stream,
                       emb, Abf, Tg, Dg, done, out);
    hipLaunchKernelGGL(loss_kernel, dim3(NSTRIPS), dim3(512), 0, stream,
                       Abf, Tg, Dg, done, out);
}